// Round 14
// baseline (149.806 us; speedup 1.0000x reference)
//
#include <hip/hip_runtime.h>
#include <math.h>

// SineSPE R14: R13 champion math + all-wave-private sync. Each wave DMAs its OWN
// 4 B column-frags (benign duplicate writes; L2-resident) -> B needs only a
// wave-local counted vmcnt(4), no barrier. A double-buffered -> ONE barrier per
// chunk (protects A(t+1) write vs MFMA(t-1) readers). Synth/epilogue/prep/XCD
// decode byte-identical to R13. Fallback: validated R2-family kernel.

#define NH 8
#define NF 64
#define NK 10
#define NR 256
#define NB 4
#define NL 2048
#define KTOT 1280
#define BM 128               // fallback tile
#define BK 32
#define NCH (KTOT/BK)        // 40
#define NFRAG_B 16
#define WS_NEEDED ((size_t)NB*NH*NCH*NFRAG_B*1024)   // 20,971,520 B

typedef __attribute__((ext_vector_type(8))) short short8;
typedef __attribute__((ext_vector_type(4))) float f32x4;
typedef __attribute__((ext_vector_type(4))) unsigned int u32x4;
typedef __attribute__((ext_vector_type(2))) unsigned int u32x2;

static __device__ __forceinline__ unsigned short f2b(float f) {  // fp32->bf16 RNE
    unsigned x = __float_as_uint(f);
    return (unsigned short)((x + 0x7FFFu + ((x >> 16) & 1u)) >> 16);
}
static __device__ __forceinline__ unsigned int pk2(float a, float b) {
    return (unsigned int)f2b(a) | ((unsigned int)f2b(b) << 16);
}
static __device__ __forceinline__ unsigned int cvtpk(float lo, float hi) {
    unsigned int r;
    asm("v_cvt_pk_bf16_f32 %0, %1, %2" : "=v"(r) : "v"(lo), "v"(hi));
    return r;
}
static __device__ __forceinline__ void gload_lds16(const void* g, void* l) {
    __builtin_amdgcn_global_load_lds(
        (const __attribute__((address_space(1))) unsigned int*)g,
        (__attribute__((address_space(3))) unsigned int*)l, 16, 0, 0);
}

// ---------------- prep: z -> bf16 frag-ordered Bpack (gains folded) ----------
__global__ __launch_bounds__(256)
void spe_prep(const float* __restrict__ z, const float* __restrict__ gains,
              unsigned char* __restrict__ bpack)
{
    __shared__ float s_g[NF*NK];
    const int ch  = blockIdx.x;
    const int bh  = blockIdx.y;
    const int h   = bh & 7;
    const int tid = threadIdx.x;
    for (int i = tid; i < NF*NK; i += 256)
        s_g[i] = log1pf(expf(gains[h*NF*NK + i])) * 0.0078125f;  // softplus/128
    __syncthreads();
    const float* zb = z + (size_t)bh * KTOT * NR;
    unsigned char* dst = bpack + ((size_t)(bh*NCH + ch) * NFRAG_B) * 1024;
    #pragma unroll
    for (int it = 0; it < 4; ++it) {
        const int s  = tid + 256*it;
        const int fi = s >> 6;
        const int l  = s & 63;
        const int r  = fi*16 + (l & 15);
        const int k0 = ch*BK + (l >> 4)*8;
        u32x4 wv;
        #pragma unroll
        for (int jp = 0; jp < 4; ++jp) {
            const int ka = k0 + 2*jp, kb = ka + 1;
            const int fa = (ka*3277) >> 16; int sa = ka - fa*20; if (sa >= NK) sa -= NK;
            const int fb = (kb*3277) >> 16; int sb = kb - fb*20; if (sb >= NK) sb -= NK;
            const float va = zb[(size_t)ka*NR + r] * s_g[fa*NK + sa];
            const float vb = zb[(size_t)kb*NR + r] * s_g[fb*NK + sb];
            wv[jp] = pk2(va, vb);
        }
        *(u32x4*)(dst + (size_t)s*16) = wv;
    }
}

// ---------------- main8: wave-private B, A-dbuf, 1 barrier/chunk -------------
#define OFF_B0  0              // 16 KiB
#define OFF_B1  16384          // 16 KiB
#define OFF_A   32768          // 2 x 8 KiB (XOR-swizzled frag images)
#define OFF_POS 49152          // [2 qk][64 f][64 rows] bf16 = 16384 B
#define OFF_FR  65536          // 640 f32
#define OFF_CO  68096          // 640 f32
#define OFF_SO  70656          // 640 f32
#define SMEM_SZ 73216          // 71.5 KiB -> 2 blocks/CU

__global__ __launch_bounds__(512, 4)
void spe_main(const float* __restrict__ queries, const float* __restrict__ keys,
              const float* __restrict__ freqs, const float* __restrict__ offsets,
              const unsigned char* __restrict__ bpack, float* __restrict__ out)
{
    __shared__ __attribute__((aligned(16))) unsigned char smem[SMEM_SZ];
    const int tid  = threadIdx.x;
    const int lane = tid & 63;
    const int w    = tid >> 6;

    // XCD-locality decode (validated R13): bid&7 = h
    const int fb = blockIdx.x;              // 0..1023
    const int h  = fb & 7;
    const int b  = (fb >> 3) & 3;
    const int l0 = (fb >> 5) * 64;
    const int bh = b*NH + h;

    float* ld_fr = (float*)(smem + OFF_FR);
    float* ld_co = (float*)(smem + OFF_CO);
    float* ld_so = (float*)(smem + OFF_SO);
    unsigned short* pos_t = (unsigned short*)(smem + OFF_POS);

    for (int i = tid; i < NF*NK; i += 512) {
        const float fv = freqs[h*NF*NK + i];
        ld_fr[i] = 0.5f / (1.0f + expf(-fv));                                // rev/step
        const float xo = __builtin_amdgcn_fractf(offsets[h*NF*NK + i] * 0.15915494309189535f);
        ld_co[i] = __builtin_amdgcn_cosf(xo);
        ld_so[i] = __builtin_amdgcn_sinf(xo);
    }
    {   // pos tiles -> bf16 transposed [qk][f][64]
        const int r  = tid >> 2;            // 0..127: <64 q-row, >=64 k-row
        const int f0 = (tid & 3) * 16;
        const int rl = r & 63;
        const float* src = (r < 64)
            ? queries + ((size_t)((b*NL + l0 + rl)*NH + h))*NF + f0
            : keys    + ((size_t)((b*NL + l0 + rl)*NH + h))*NF + f0;
        unsigned short* pdst = pos_t + ((r >> 6) << 12);
        #pragma unroll
        for (int j = 0; j < 4; ++j) {
            const float4 v = *(const float4*)(src + j*4);
            const int f = f0 + j*4;
            pdst[(f+0)*64 + rl] = f2b(v.x);
            pdst[(f+1)*64 + rl] = f2b(v.y);
            pdst[(f+2)*64 + rl] = f2b(v.z);
            pdst[(f+3)*64 + rl] = f2b(v.w);
        }
    }
    __syncthreads();   // pos/cs tables visible

    const unsigned char* bp = bpack + (size_t)bh * ((size_t)NCH*NFRAG_B*1024);

    const int wm = w >> 2, wn = w & 3;      // wm=0 -> q-half, wm=1 -> k-half
    const int fn0 = wn * 4;                 // this wave's 4 B column-frags

    // issue B(t) -> Bbuf[t&1] (wave-private: the frags THIS wave reads)
    auto issueB = [&](int t) {
        unsigned char* Bd = smem + ((t & 1) ? OFF_B1 : OFF_B0);
        const unsigned char* bsrc = bp + (size_t)t*NFRAG_B*1024;
        #pragma unroll
        for (int j = 0; j < 4; ++j)
            gload_lds16(bsrc + (size_t)(fn0 + j)*1024 + lane*16,
                        Bd + ((fn0 + j) << 10));
    };

    f32x4 acc[4][4];
    #pragma unroll
    for (int mi = 0; mi < 4; ++mi)
        #pragma unroll
        for (int ni = 0; ni < 4; ++ni)
            acc[mi][ni] = (f32x4){0.f, 0.f, 0.f, 0.f};

    // A-synth map (R13-validated): rq = tid&63, oct = (tid>>6)&3, half = tid>>8
    const int rq   = tid & 63;
    const int oct  = (tid >> 6) & 3;
    const int half = tid >> 8;
    const float lf = (float)(l0 + rq);
    const unsigned short* posq = pos_t;
    const unsigned short* posk = pos_t + 4096;
    const int a_log_q = ((rq >> 4) << 10) + ((oct*16 + (rq & 15)) << 4) + (half << 3);
    const int aw_q = a_log_q ^ (((rq >> 4) & 3) << 5);
    const int aw_k = (a_log_q + 4096) ^ (((rq >> 4) & 3) << 5);

    auto synthA = [&](int t, u32x2& q01, u32x2& k01) {
        #pragma unroll
        for (int p = 0; p < 2; ++p) {
            const int kk   = t*BK + oct*8 + (half*2 + p)*2;   // even k
            const int f    = (kk*3277) >> 16;                 // kk/20
            const int srem = kk - f*20;
            const int kidx = f*NK + (srem >> 1);
            const float x  = __builtin_amdgcn_fractf(ld_fr[kidx] * lf);
            const float ck = __builtin_amdgcn_cosf(x);
            const float sk = __builtin_amdgcn_sinf(x);
            const float co = ld_co[kidx], so = ld_so[kidx];
            const float cq = ck*co - sk*so;                   // rotate by offset
            const float sq = sk*co + ck*so;
            const float pq = __uint_as_float(((unsigned)posq[f*64 + rq]) << 16);
            const float pk = __uint_as_float(((unsigned)posk[f*64 + rq]) << 16);
            q01[p] = cvtpk(cq*pq, sq*pq);
            k01[p] = cvtpk(ck*pk, sk*pk);
        }
    };

    // prologue: A(0) -> Abuf0, synth A(1) -> regs, issue B(0); barrier (A0 visible)
    u32x2 q01, k01;
    synthA(0, q01, k01);
    *(u32x2*)(smem + OFF_A + aw_q) = q01;       // Abuf0 (par=0)
    *(u32x2*)(smem + OFF_A + aw_k) = k01;
    issueB(0);
    synthA(1, q01, k01);
    __builtin_amdgcn_sched_barrier(0);
    __builtin_amdgcn_s_barrier();               // A(0) visible to all waves
    __builtin_amdgcn_sched_barrier(0);

    #pragma unroll 1
    for (int t = 0; t < NCH; ++t) {
        const int par = t & 1;

        if (t + 1 < NCH) {
            // write A(t+1) -> other A buffer (its MFMA(t-1) readers passed the barrier)
            const int np = (t + 1) & 1;
            *(u32x2*)(smem + OFF_A + np*8192 + aw_q) = q01;
            *(u32x2*)(smem + OFF_A + np*8192 + aw_k) = k01;
            issueB(t + 1);                       // into Bbuf[(t+1)&1]; readers done pre-barrier
        }
        if (t + 2 < NCH) synthA(t + 2, q01, k01);   // VALU (overlaps other waves' MFMA)

        // wave-local wait: B(t) landed (issued a full chunk ago; 4 newer loads allowed)
        if (t + 1 < NCH) { asm volatile("s_waitcnt vmcnt(4)" ::: "memory"); }
        else             { asm volatile("s_waitcnt vmcnt(0)" ::: "memory"); }
        __builtin_amdgcn_sched_barrier(0);

        const unsigned char* Bc = smem + (par ? OFF_B1 : OFF_B0);
        short8 bf[4];
        #pragma unroll
        for (int ni = 0; ni < 4; ++ni)
            bf[ni] = *(const short8*)(Bc + ((fn0 + ni) << 10) + (lane << 4));

        #pragma unroll
        for (int mi = 0; mi < 4; ++mi) {
            const int g    = wm*4 + mi;
            const int aoff = (g << 10) + (lane << 4);
            const short8 af = *(const short8*)(smem + OFF_A + par*8192
                                               + (aoff ^ ((g & 3) << 5)));
            #pragma unroll
            for (int ni = 0; ni < 4; ++ni)
                acc[mi][ni] = __builtin_amdgcn_mfma_f32_16x16x32_bf16(af, bf[ni], acc[mi][ni], 0, 0, 0);
        }

        if (t + 1 < NCH) {                       // end-of-chunk barrier (A protection)
            __builtin_amdgcn_sched_barrier(0);
            __builtin_amdgcn_s_barrier();
            __builtin_amdgcn_sched_barrier(0);
        }
    }

    // epilogue (R13-validated): wm selects q/k; C/D col=lane&15, row=(lane>>4)*4+reg
    const size_t qk_off = (size_t)wm * ((size_t)NB*NL*NH*NR);
    const int row_l = (lane >> 4) * 4;
    const int col_r = lane & 15;
    #pragma unroll
    for (int mi = 0; mi < 4; ++mi) {
        const int lg = l0 + mi*16 + row_l;
        #pragma unroll
        for (int ni = 0; ni < 4; ++ni) {
            const int rg = wn*64 + ni*16 + col_r;
            const f32x4 v = acc[mi][ni];
            #pragma unroll
            for (int q = 0; q < 4; ++q)
                out[qk_off + ((size_t)((b*NL + lg + q)*NH + h))*NR + rg] = v[q];
        }
    }
}

// ---------------- fallback (validated R2 kernel) ----------------
#define FOFF_B   0
#define FOFF_A   32768
#define FOFF_POS 49152
#define FOFF_FR  65536
#define FOFF_OFS 68096
#define FOFF_GS  70656
#define FSMEM_SZ 73216

__global__ __launch_bounds__(512, 4)
void spe_mfma_fb(const float* __restrict__ queries, const float* __restrict__ keys,
                 const float* __restrict__ z, const float* __restrict__ freqs,
                 const float* __restrict__ offsets, const float* __restrict__ gains,
                 float* __restrict__ out)
{
    __shared__ __attribute__((aligned(16))) unsigned char smem[FSMEM_SZ];
    const int tid = threadIdx.x, lane = tid & 63;
    const int l0 = blockIdx.x * BM, bh = blockIdx.y;
    const int b = bh >> 3, h = bh & 7, isK = blockIdx.z;
    float* ld_fr = (float*)(smem + FOFF_FR);
    float* ld_of = (float*)(smem + FOFF_OFS);
    float* ld_gs = (float*)(smem + FOFF_GS);
    unsigned short* pos_t = (unsigned short*)(smem + FOFF_POS);
    for (int i = tid; i < NF*NK; i += 512) {
        const float fv = freqs[h*NF*NK + i];
        ld_fr[i] = 0.5f / (1.0f + expf(-fv));
        ld_of[i] = isK ? 0.0f : offsets[h*NF*NK + i] * 0.15915494309189535f;
        ld_gs[i] = log1pf(expf(gains[h*NF*NK + i])) * 0.0078125f;
    }
    {
        const float* pos = isK ? keys : queries;
        #pragma unroll
        for (int i = 0; i < 4; ++i) {
            const int lrow = (tid >> 4) + 32*i;
            const int f0 = (tid & 15) * 4;
            const float4 v = *(const float4*)(pos + ((size_t)((b*NL + l0 + lrow)*NH + h))*NF + f0);
            pos_t[(f0+0)*BM + lrow] = f2b(v.x); pos_t[(f0+1)*BM + lrow] = f2b(v.y);
            pos_t[(f0+2)*BM + lrow] = f2b(v.z); pos_t[(f0+3)*BM + lrow] = f2b(v.w);
        }
    }
    __syncthreads();
    const int w = tid >> 6, wm = w >> 2, wn = w & 3;
    f32x4 acc[4][4];
    #pragma unroll
    for (int mi = 0; mi < 4; ++mi)
        #pragma unroll
        for (int ni = 0; ni < 4; ++ni) acc[mi][ni] = (f32x4){0.f,0.f,0.f,0.f};
    const float* zbh = z + (size_t)(b*NH + h) * ((size_t)KTOT*NR);
    for (int ch = 0; ch < KTOT/64; ++ch) {
        const int fs0 = ch * 64;
        #pragma unroll
        for (int i = 0; i < 4; ++i) {
            const int tau = tid + 512*i, r = tau & 255, krun = tau >> 8;
            const float* zp = zbh + (size_t)(fs0 + krun*8)*NR + r;
            u32x4 wv2;
            #pragma unroll
            for (int jp = 0; jp < 4; ++jp) {
                const int fs = fs0 + krun*8 + 2*jp;
                const int f = (fs*3277) >> 16; const int rem = fs - f*20;
                const int km = (rem >= NK) ? rem - NK : rem;
                const int kn = ((rem+1) >= NK && (rem+1) < 2*NK) ? rem+1-NK : rem+1;
                const float sc0 = ld_gs[f*NK + km], sc1 = ld_gs[f*NK + (kn < NK ? kn : kn-NK)];
                wv2[jp] = pk2(zp[(2*jp)*NR]*sc0, zp[(2*jp+1)*NR]*sc1);
            }
            *(u32x4*)(smem + FOFF_B + ((((krun>>2)*16) + (r>>4)) << 10)
                                    + ((((krun&3)*16) + (r&15)) << 4)) = wv2;
        }
        #pragma unroll
        for (int i = 0; i < 2; ++i) {
            const int tau = tid + 512*i, m = tau & 127, krun = tau >> 7;
            const float lff = (float)(l0 + m);
            u32x4 wv2;
            #pragma unroll
            for (int jp = 0; jp < 4; ++jp) {
                const int fs = fs0 + krun*8 + 2*jp;
                const int f = (fs*3277) >> 16; const int rem = fs - f*20;
                const int kidx = f*NK + (rem >> 1);
                const float x = __builtin_amdgcn_fractf(ld_of[kidx] + ld_fr[kidx]*lff);
                const float c = __builtin_amdgcn_cosf(x), sn = __builtin_amdgcn_sinf(x);
                const float p = __uint_as_float(((unsigned)pos_t[f*BM + m]) << 16);
                wv2[jp] = pk2(c*p, sn*p);
            }
            *(u32x4*)(smem + FOFF_A + ((((krun>>2)*8) + (m>>4)) << 10)
                                    + ((((krun&3)*16) + (m&15)) << 4)) = wv2;
        }
        __syncthreads();
        #pragma unroll
        for (int ks = 0; ks < 2; ++ks) {
            short8 bf[4];
            #pragma unroll
            for (int ni = 0; ni < 4; ++ni)
                bf[ni] = *(const short8*)(smem + FOFF_B + ((ks*16 + wn*4 + ni) << 10) + (lane << 4));
            #pragma unroll
            for (int mi = 0; mi < 4; ++mi) {
                const short8 af = *(const short8*)(smem + FOFF_A + ((ks*8 + wm*4 + mi) << 10) + (lane << 4));
                #pragma unroll
                for (int ni = 0; ni < 4; ++ni)
                    acc[mi][ni] = __builtin_amdgcn_mfma_f32_16x16x32_bf16(af, bf[ni], acc[mi][ni], 0, 0, 0);
            }
        }
        __syncthreads();
    }
    const size_t qk_off = (size_t)isK * ((size_t)NB*NL*NH*NR);
    const int row_l = (lane >> 4) * 4, col_r = lane & 15;
    #pragma unroll
    for (int mi = 0; mi < 4; ++mi) {
        const int lg = l0 + wm*64 + mi*16 + row_l;
        #pragma unroll
        for (int ni = 0; ni < 4; ++ni) {
            const int rg = wn*64 + ni*16 + col_r;
            const f32x4 v = acc[mi][ni];
            #pragma unroll
            for (int q = 0; q < 4; ++q)
                out[qk_off + ((size_t)((b*NL + lg + q)*NH + h))*NR + rg] = v[q];
        }
    }
}

extern "C" void kernel_launch(void* const* d_in, const int* in_sizes, int n_in,
                              void* d_out, int out_size, void* d_ws, size_t ws_size,
                              hipStream_t stream) {
    const float* queries = (const float*)d_in[0];
    const float* keys    = (const float*)d_in[1];
    const float* z       = (const float*)d_in[2];
    const float* freqs   = (const float*)d_in[3];
    const float* offsets = (const float*)d_in[4];
    const float* gains   = (const float*)d_in[5];
    float* out = (float*)d_out;

    if (ws_size >= WS_NEEDED) {
        unsigned char* bpack = (unsigned char*)d_ws;
        spe_prep<<<dim3(NCH, NB*NH), 256, 0, stream>>>(z, gains, bpack);
        spe_main<<<dim3(1024), 512, 0, stream>>>(queries, keys, freqs, offsets, bpack, out);
    } else {
        spe_mfma_fb<<<dim3(NL/BM, NB*NH, 2), 512, 0, stream>>>(queries, keys, z, freqs, offsets, gains, out);
    }
}

// Round 15
// 124.517 us; speedup vs baseline: 1.2031x; 1.2031x over previous
//
#include <hip/hip_runtime.h>
#include <math.h>

// SineSPE R15: R14's validated 1-barrier sync + DEDUPED wave-private B via
// column ownership: wave w stages B frags [2w,2w+1] (2 gload_lds/chunk, no
// duplication) and computes the full 128-row (q+k) x 32-col strip (acc 8x2).
// B wait = wave-local vmcnt(2), pre-satisfied (full-chunk flight). One barrier
// per chunk protects the A double-buffer. Synth/prep/XCD decode = R13 champion.

#define NH 8
#define NF 64
#define NK 10
#define NR 256
#define NB 4
#define NL 2048
#define KTOT 1280
#define BM 128               // fallback tile
#define BK 32
#define NCH (KTOT/BK)        // 40
#define NFRAG_B 16
#define WS_NEEDED ((size_t)NB*NH*NCH*NFRAG_B*1024)   // 20,971,520 B

typedef __attribute__((ext_vector_type(8))) short short8;
typedef __attribute__((ext_vector_type(4))) float f32x4;
typedef __attribute__((ext_vector_type(4))) unsigned int u32x4;
typedef __attribute__((ext_vector_type(2))) unsigned int u32x2;

static __device__ __forceinline__ unsigned short f2b(float f) {  // fp32->bf16 RNE
    unsigned x = __float_as_uint(f);
    return (unsigned short)((x + 0x7FFFu + ((x >> 16) & 1u)) >> 16);
}
static __device__ __forceinline__ unsigned int pk2(float a, float b) {
    return (unsigned int)f2b(a) | ((unsigned int)f2b(b) << 16);
}
static __device__ __forceinline__ unsigned int cvtpk(float lo, float hi) {
    unsigned int r;
    asm("v_cvt_pk_bf16_f32 %0, %1, %2" : "=v"(r) : "v"(lo), "v"(hi));
    return r;
}
static __device__ __forceinline__ void gload_lds16(const void* g, void* l) {
    __builtin_amdgcn_global_load_lds(
        (const __attribute__((address_space(1))) unsigned int*)g,
        (__attribute__((address_space(3))) unsigned int*)l, 16, 0, 0);
}

// ---------------- prep: z -> bf16 frag-ordered Bpack (gains folded) ----------
__global__ __launch_bounds__(256)
void spe_prep(const float* __restrict__ z, const float* __restrict__ gains,
              unsigned char* __restrict__ bpack)
{
    __shared__ float s_g[NF*NK];
    const int ch  = blockIdx.x;
    const int bh  = blockIdx.y;
    const int h   = bh & 7;
    const int tid = threadIdx.x;
    for (int i = tid; i < NF*NK; i += 256)
        s_g[i] = log1pf(expf(gains[h*NF*NK + i])) * 0.0078125f;  // softplus/128
    __syncthreads();
    const float* zb = z + (size_t)bh * KTOT * NR;
    unsigned char* dst = bpack + ((size_t)(bh*NCH + ch) * NFRAG_B) * 1024;
    #pragma unroll
    for (int it = 0; it < 4; ++it) {
        const int s  = tid + 256*it;
        const int fi = s >> 6;
        const int l  = s & 63;
        const int r  = fi*16 + (l & 15);
        const int k0 = ch*BK + (l >> 4)*8;
        u32x4 wv;
        #pragma unroll
        for (int jp = 0; jp < 4; ++jp) {
            const int ka = k0 + 2*jp, kb = ka + 1;
            const int fa = (ka*3277) >> 16; int sa = ka - fa*20; if (sa >= NK) sa -= NK;
            const int fb = (kb*3277) >> 16; int sb = kb - fb*20; if (sb >= NK) sb -= NK;
            const float va = zb[(size_t)ka*NR + r] * s_g[fa*NK + sa];
            const float vb = zb[(size_t)kb*NR + r] * s_g[fb*NK + sb];
            wv[jp] = pk2(va, vb);
        }
        *(u32x4*)(dst + (size_t)s*16) = wv;
    }
}

// ---------------- main9: col-owned wave-private B, A-dbuf, 1 barrier/chunk ---
#define OFF_B0  0              // 16 KiB
#define OFF_B1  16384          // 16 KiB
#define OFF_A   32768          // 2 x 8 KiB (XOR-swizzled frag images)
#define OFF_POS 49152          // [2 qk][64 f][64 rows] bf16 = 16384 B
#define OFF_FR  65536          // 640 f32
#define OFF_CO  68096          // 640 f32
#define OFF_SO  70656          // 640 f32
#define SMEM_SZ 73216          // 71.5 KiB -> 2 blocks/CU

__global__ __launch_bounds__(512, 4)
void spe_main(const float* __restrict__ queries, const float* __restrict__ keys,
              const float* __restrict__ freqs, const float* __restrict__ offsets,
              const unsigned char* __restrict__ bpack, float* __restrict__ out)
{
    __shared__ __attribute__((aligned(16))) unsigned char smem[SMEM_SZ];
    const int tid  = threadIdx.x;
    const int lane = tid & 63;
    const int w    = tid >> 6;

    // XCD-locality decode (validated R13): bid&7 = h
    const int fb = blockIdx.x;              // 0..1023
    const int h  = fb & 7;
    const int b  = (fb >> 3) & 3;
    const int l0 = (fb >> 5) * 64;
    const int bh = b*NH + h;

    float* ld_fr = (float*)(smem + OFF_FR);
    float* ld_co = (float*)(smem + OFF_CO);
    float* ld_so = (float*)(smem + OFF_SO);
    unsigned short* pos_t = (unsigned short*)(smem + OFF_POS);

    for (int i = tid; i < NF*NK; i += 512) {
        const float fv = freqs[h*NF*NK + i];
        ld_fr[i] = 0.5f / (1.0f + expf(-fv));                                // rev/step
        const float xo = __builtin_amdgcn_fractf(offsets[h*NF*NK + i] * 0.15915494309189535f);
        ld_co[i] = __builtin_amdgcn_cosf(xo);
        ld_so[i] = __builtin_amdgcn_sinf(xo);
    }
    {   // pos tiles -> bf16 transposed [qk][f][64]
        const int r  = tid >> 2;            // 0..127: <64 q-row, >=64 k-row
        const int f0 = (tid & 3) * 16;
        const int rl = r & 63;
        const float* src = (r < 64)
            ? queries + ((size_t)((b*NL + l0 + rl)*NH + h))*NF + f0
            : keys    + ((size_t)((b*NL + l0 + rl)*NH + h))*NF + f0;
        unsigned short* pdst = pos_t + ((r >> 6) << 12);
        #pragma unroll
        for (int j = 0; j < 4; ++j) {
            const float4 v = *(const float4*)(src + j*4);
            const int f = f0 + j*4;
            pdst[(f+0)*64 + rl] = f2b(v.x);
            pdst[(f+1)*64 + rl] = f2b(v.y);
            pdst[(f+2)*64 + rl] = f2b(v.z);
            pdst[(f+3)*64 + rl] = f2b(v.w);
        }
    }
    __syncthreads();   // pos/cs tables visible

    const unsigned char* bp = bpack + (size_t)bh * ((size_t)NCH*NFRAG_B*1024);

    const int fn0 = w * 2;                  // this wave OWNS B col-frags 2w, 2w+1

    // issue B(t) -> Bbuf[t&1] (only the frags THIS wave reads; no duplication)
    auto issueB = [&](int t) {
        unsigned char* Bd = smem + ((t & 1) ? OFF_B1 : OFF_B0);
        const unsigned char* bsrc = bp + (size_t)t*NFRAG_B*1024;
        #pragma unroll
        for (int j = 0; j < 2; ++j)
            gload_lds16(bsrc + (size_t)(fn0 + j)*1024 + lane*16,
                        Bd + ((fn0 + j) << 10));
    };

    f32x4 acc[8][2];   // 8 row-frags (0-3 q, 4-7 k) x 2 col-frags = 64 AGPR
    #pragma unroll
    for (int mi = 0; mi < 8; ++mi)
        #pragma unroll
        for (int ni = 0; ni < 2; ++ni)
            acc[mi][ni] = (f32x4){0.f, 0.f, 0.f, 0.f};

    // A-synth map (R13-validated): rq = tid&63, oct = (tid>>6)&3, half = tid>>8
    const int rq   = tid & 63;
    const int oct  = (tid >> 6) & 3;
    const int half = tid >> 8;
    const float lf = (float)(l0 + rq);
    const unsigned short* posq = pos_t;
    const unsigned short* posk = pos_t + 4096;
    const int a_log_q = ((rq >> 4) << 10) + ((oct*16 + (rq & 15)) << 4) + (half << 3);
    const int aw_q = a_log_q ^ (((rq >> 4) & 3) << 5);
    const int aw_k = (a_log_q + 4096) ^ (((rq >> 4) & 3) << 5);

    auto synthA = [&](int t, u32x2& q01, u32x2& k01) {
        #pragma unroll
        for (int p = 0; p < 2; ++p) {
            const int kk   = t*BK + oct*8 + (half*2 + p)*2;   // even k
            const int f    = (kk*3277) >> 16;                 // kk/20
            const int srem = kk - f*20;
            const int kidx = f*NK + (srem >> 1);
            const float x  = __builtin_amdgcn_fractf(ld_fr[kidx] * lf);
            const float ck = __builtin_amdgcn_cosf(x);
            const float sk = __builtin_amdgcn_sinf(x);
            const float co = ld_co[kidx], so = ld_so[kidx];
            const float cq = ck*co - sk*so;                   // rotate by offset
            const float sq = sk*co + ck*so;
            const float pq = __uint_as_float(((unsigned)posq[f*64 + rq]) << 16);
            const float pk = __uint_as_float(((unsigned)posk[f*64 + rq]) << 16);
            q01[p] = cvtpk(cq*pq, sq*pq);
            k01[p] = cvtpk(ck*pk, sk*pk);
        }
    };

    // prologue: A(0) -> Abuf0, synth A(1) -> regs, issue B(0); barrier (A0 visible)
    u32x2 q01, k01;
    synthA(0, q01, k01);
    *(u32x2*)(smem + OFF_A + aw_q) = q01;       // Abuf0 (par=0)
    *(u32x2*)(smem + OFF_A + aw_k) = k01;
    issueB(0);
    synthA(1, q01, k01);
    __builtin_amdgcn_sched_barrier(0);
    __builtin_amdgcn_s_barrier();               // A(0) visible to all waves
    __builtin_amdgcn_sched_barrier(0);

    #pragma unroll 1
    for (int t = 0; t < NCH; ++t) {
        const int par = t & 1;

        if (t + 1 < NCH) {
            // write A(t+1) -> other A buffer (its MFMA(t-1) readers passed the barrier)
            const int np = (t + 1) & 1;
            *(u32x2*)(smem + OFF_A + np*8192 + aw_q) = q01;
            *(u32x2*)(smem + OFF_A + np*8192 + aw_k) = k01;
            issueB(t + 1);                       // Bbuf[(t+1)&1]; own reads(t-1) retired
        }
        if (t + 2 < NCH) synthA(t + 2, q01, k01);   // VALU (overlaps other waves' MFMA)

        // wave-local wait: B(t) landed (issued a full chunk ago; 2 newer loads allowed)
        if (t + 1 < NCH) { asm volatile("s_waitcnt vmcnt(2)" ::: "memory"); }
        else             { asm volatile("s_waitcnt vmcnt(0)" ::: "memory"); }
        __builtin_amdgcn_sched_barrier(0);

        const unsigned char* Bc = smem + (par ? OFF_B1 : OFF_B0);
        short8 bf[2];
        #pragma unroll
        for (int ni = 0; ni < 2; ++ni)
            bf[ni] = *(const short8*)(Bc + ((fn0 + ni) << 10) + (lane << 4));

        #pragma unroll
        for (int mi = 0; mi < 8; ++mi) {         // all 8 A frags (q rows then k rows)
            const int aoff = (mi << 10) + (lane << 4);
            const short8 af = *(const short8*)(smem + OFF_A + par*8192
                                               + (aoff ^ ((mi & 3) << 5)));
            #pragma unroll
            for (int ni = 0; ni < 2; ++ni)
                acc[mi][ni] = __builtin_amdgcn_mfma_f32_16x16x32_bf16(af, bf[ni], acc[mi][ni], 0, 0, 0);
        }

        if (t + 1 < NCH) {                       // end-of-chunk barrier (A protection)
            __builtin_amdgcn_sched_barrier(0);
            __builtin_amdgcn_s_barrier();
            __builtin_amdgcn_sched_barrier(0);
        }
    }

    // epilogue: mi>>2 selects q/k; rows (mi&3)*16; cols = wave strip w*32 + ni*16
    const size_t kofs = (size_t)NB*NL*NH*NR;
    const int row_l = (lane >> 4) * 4;
    const int col_r = lane & 15;
    #pragma unroll
    for (int mi = 0; mi < 8; ++mi) {
        const size_t qk_off = (mi >= 4) ? kofs : 0;
        const int lg = l0 + (mi & 3)*16 + row_l;
        #pragma unroll
        for (int ni = 0; ni < 2; ++ni) {
            const int rg = w*32 + ni*16 + col_r;
            const f32x4 v = acc[mi][ni];
            #pragma unroll
            for (int q = 0; q < 4; ++q)
                out[qk_off + ((size_t)((b*NL + lg + q)*NH + h))*NR + rg] = v[q];
        }
    }
}

// ---------------- fallback (validated R2 kernel) ----------------
#define FOFF_B   0
#define FOFF_A   32768
#define FOFF_POS 49152
#define FOFF_FR  65536
#define FOFF_OFS 68096
#define FOFF_GS  70656
#define FSMEM_SZ 73216

__global__ __launch_bounds__(512, 4)
void spe_mfma_fb(const float* __restrict__ queries, const float* __restrict__ keys,
                 const float* __restrict__ z, const float* __restrict__ freqs,
                 const float* __restrict__ offsets, const float* __restrict__ gains,
                 float* __restrict__ out)
{
    __shared__ __attribute__((aligned(16))) unsigned char smem[FSMEM_SZ];
    const int tid = threadIdx.x, lane = tid & 63;
    const int l0 = blockIdx.x * BM, bh = blockIdx.y;
    const int b = bh >> 3, h = bh & 7, isK = blockIdx.z;
    float* ld_fr = (float*)(smem + FOFF_FR);
    float* ld_of = (float*)(smem + FOFF_OFS);
    float* ld_gs = (float*)(smem + FOFF_GS);
    unsigned short* pos_t = (unsigned short*)(smem + FOFF_POS);
    for (int i = tid; i < NF*NK; i += 512) {
        const float fv = freqs[h*NF*NK + i];
        ld_fr[i] = 0.5f / (1.0f + expf(-fv));
        ld_of[i] = isK ? 0.0f : offsets[h*NF*NK + i] * 0.15915494309189535f;
        ld_gs[i] = log1pf(expf(gains[h*NF*NK + i])) * 0.0078125f;
    }
    {
        const float* pos = isK ? keys : queries;
        #pragma unroll
        for (int i = 0; i < 4; ++i) {
            const int lrow = (tid >> 4) + 32*i;
            const int f0 = (tid & 15) * 4;
            const float4 v = *(const float4*)(pos + ((size_t)((b*NL + l0 + lrow)*NH + h))*NF + f0);
            pos_t[(f0+0)*BM + lrow] = f2b(v.x); pos_t[(f0+1)*BM + lrow] = f2b(v.y);
            pos_t[(f0+2)*BM + lrow] = f2b(v.z); pos_t[(f0+3)*BM + lrow] = f2b(v.w);
        }
    }
    __syncthreads();
    const int w = tid >> 6, wm = w >> 2, wn = w & 3;
    f32x4 acc[4][4];
    #pragma unroll
    for (int mi = 0; mi < 4; ++mi)
        #pragma unroll
        for (int ni = 0; ni < 4; ++ni) acc[mi][ni] = (f32x4){0.f,0.f,0.f,0.f};
    const float* zbh = z + (size_t)(b*NH + h) * ((size_t)KTOT*NR);
    for (int ch = 0; ch < KTOT/64; ++ch) {
        const int fs0 = ch * 64;
        #pragma unroll
        for (int i = 0; i < 4; ++i) {
            const int tau = tid + 512*i, r = tau & 255, krun = tau >> 8;
            const float* zp = zbh + (size_t)(fs0 + krun*8)*NR + r;
            u32x4 wv2;
            #pragma unroll
            for (int jp = 0; jp < 4; ++jp) {
                const int fs = fs0 + krun*8 + 2*jp;
                const int f = (fs*3277) >> 16; const int rem = fs - f*20;
                const int km = (rem >= NK) ? rem - NK : rem;
                const int kn = ((rem+1) >= NK && (rem+1) < 2*NK) ? rem+1-NK : rem+1;
                const float sc0 = ld_gs[f*NK + km], sc1 = ld_gs[f*NK + (kn < NK ? kn : kn-NK)];
                wv2[jp] = pk2(zp[(2*jp)*NR]*sc0, zp[(2*jp+1)*NR]*sc1);
            }
            *(u32x4*)(smem + FOFF_B + ((((krun>>2)*16) + (r>>4)) << 10)
                                    + ((((krun&3)*16) + (r&15)) << 4)) = wv2;
        }
        #pragma unroll
        for (int i = 0; i < 2; ++i) {
            const int tau = tid + 512*i, m = tau & 127, krun = tau >> 7;
            const float lff = (float)(l0 + m);
            u32x4 wv2;
            #pragma unroll
            for (int jp = 0; jp < 4; ++jp) {
                const int fs = fs0 + krun*8 + 2*jp;
                const int f = (fs*3277) >> 16; const int rem = fs - f*20;
                const int kidx = f*NK + (rem >> 1);
                const float x = __builtin_amdgcn_fractf(ld_of[kidx] + ld_fr[kidx]*lff);
                const float c = __builtin_amdgcn_cosf(x), sn = __builtin_amdgcn_sinf(x);
                const float p = __uint_as_float(((unsigned)pos_t[f*BM + m]) << 16);
                wv2[jp] = pk2(c*p, sn*p);
            }
            *(u32x4*)(smem + FOFF_A + ((((krun>>2)*8) + (m>>4)) << 10)
                                    + ((((krun&3)*16) + (m&15)) << 4)) = wv2;
        }
        __syncthreads();
        #pragma unroll
        for (int ks = 0; ks < 2; ++ks) {
            short8 bf[4];
            #pragma unroll
            for (int ni = 0; ni < 4; ++ni)
                bf[ni] = *(const short8*)(smem + FOFF_B + ((ks*16 + wn*4 + ni) << 10) + (lane << 4));
            #pragma unroll
            for (int mi = 0; mi < 4; ++mi) {
                const short8 af = *(const short8*)(smem + FOFF_A + ((ks*8 + wm*4 + mi) << 10) + (lane << 4));
                #pragma unroll
                for (int ni = 0; ni < 4; ++ni)
                    acc[mi][ni] = __builtin_amdgcn_mfma_f32_16x16x32_bf16(af, bf[ni], acc[mi][ni], 0, 0, 0);
            }
        }
        __syncthreads();
    }
    const size_t qk_off = (size_t)isK * ((size_t)NB*NL*NH*NR);
    const int row_l = (lane >> 4) * 4, col_r = lane & 15;
    #pragma unroll
    for (int mi = 0; mi < 4; ++mi) {
        const int lg = l0 + wm*64 + mi*16 + row_l;
        #pragma unroll
        for (int ni = 0; ni < 4; ++ni) {
            const int rg = wn*64 + ni*16 + col_r;
            const f32x4 v = acc[mi][ni];
            #pragma unroll
            for (int q = 0; q < 4; ++q)
                out[qk_off + ((size_t)((b*NL + lg + q)*NH + h))*NR + rg] = v[q];
        }
    }
}

extern "C" void kernel_launch(void* const* d_in, const int* in_sizes, int n_in,
                              void* d_out, int out_size, void* d_ws, size_t ws_size,
                              hipStream_t stream) {
    const float* queries = (const float*)d_in[0];
    const float* keys    = (const float*)d_in[1];
    const float* z       = (const float*)d_in[2];
    const float* freqs   = (const float*)d_in[3];
    const float* offsets = (const float*)d_in[4];
    const float* gains   = (const float*)d_in[5];
    float* out = (float*)d_out;

    if (ws_size >= WS_NEEDED) {
        unsigned char* bpack = (unsigned char*)d_ws;
        spe_prep<<<dim3(NCH, NB*NH), 256, 0, stream>>>(z, gains, bpack);
        spe_main<<<dim3(1024), 512, 0, stream>>>(queries, keys, freqs, offsets, bpack, out);
    } else {
        spe_mfma_fb<<<dim3(NL/BM, NB*NH, 2), 512, 0, stream>>>(queries, keys, z, freqs, offsets, gains, out);
    }
}

// Round 16
// 123.613 us; speedup vs baseline: 1.2119x; 1.0073x over previous
//
#include <hip/hip_runtime.h>
#include <math.h>

// SineSPE R16 = R15 champion + s_setprio(1) around the MFMA cluster (T5).
// R15: col-owned wave-private B (2 gload_lds/chunk, no dup), A-dbuf, ONE
// barrier per chunk, wave-local counted vmcnt, XCD decode, offset-rotation
// synth under the MFMA shadow. Math byte-identical to R15 (124.5us champion).

#define NH 8
#define NF 64
#define NK 10
#define NR 256
#define NB 4
#define NL 2048
#define KTOT 1280
#define BM 128               // fallback tile
#define BK 32
#define NCH (KTOT/BK)        // 40
#define NFRAG_B 16
#define WS_NEEDED ((size_t)NB*NH*NCH*NFRAG_B*1024)   // 20,971,520 B

typedef __attribute__((ext_vector_type(8))) short short8;
typedef __attribute__((ext_vector_type(4))) float f32x4;
typedef __attribute__((ext_vector_type(4))) unsigned int u32x4;
typedef __attribute__((ext_vector_type(2))) unsigned int u32x2;

static __device__ __forceinline__ unsigned short f2b(float f) {  // fp32->bf16 RNE
    unsigned x = __float_as_uint(f);
    return (unsigned short)((x + 0x7FFFu + ((x >> 16) & 1u)) >> 16);
}
static __device__ __forceinline__ unsigned int pk2(float a, float b) {
    return (unsigned int)f2b(a) | ((unsigned int)f2b(b) << 16);
}
static __device__ __forceinline__ unsigned int cvtpk(float lo, float hi) {
    unsigned int r;
    asm("v_cvt_pk_bf16_f32 %0, %1, %2" : "=v"(r) : "v"(lo), "v"(hi));
    return r;
}
static __device__ __forceinline__ void gload_lds16(const void* g, void* l) {
    __builtin_amdgcn_global_load_lds(
        (const __attribute__((address_space(1))) unsigned int*)g,
        (__attribute__((address_space(3))) unsigned int*)l, 16, 0, 0);
}

// ---------------- prep: z -> bf16 frag-ordered Bpack (gains folded) ----------
__global__ __launch_bounds__(256)
void spe_prep(const float* __restrict__ z, const float* __restrict__ gains,
              unsigned char* __restrict__ bpack)
{
    __shared__ float s_g[NF*NK];
    const int ch  = blockIdx.x;
    const int bh  = blockIdx.y;
    const int h   = bh & 7;
    const int tid = threadIdx.x;
    for (int i = tid; i < NF*NK; i += 256)
        s_g[i] = log1pf(expf(gains[h*NF*NK + i])) * 0.0078125f;  // softplus/128
    __syncthreads();
    const float* zb = z + (size_t)bh * KTOT * NR;
    unsigned char* dst = bpack + ((size_t)(bh*NCH + ch) * NFRAG_B) * 1024;
    #pragma unroll
    for (int it = 0; it < 4; ++it) {
        const int s  = tid + 256*it;
        const int fi = s >> 6;
        const int l  = s & 63;
        const int r  = fi*16 + (l & 15);
        const int k0 = ch*BK + (l >> 4)*8;
        u32x4 wv;
        #pragma unroll
        for (int jp = 0; jp < 4; ++jp) {
            const int ka = k0 + 2*jp, kb = ka + 1;
            const int fa = (ka*3277) >> 16; int sa = ka - fa*20; if (sa >= NK) sa -= NK;
            const int fb = (kb*3277) >> 16; int sb = kb - fb*20; if (sb >= NK) sb -= NK;
            const float va = zb[(size_t)ka*NR + r] * s_g[fa*NK + sa];
            const float vb = zb[(size_t)kb*NR + r] * s_g[fb*NK + sb];
            wv[jp] = pk2(va, vb);
        }
        *(u32x4*)(dst + (size_t)s*16) = wv;
    }
}

// ---------------- main: col-owned wave-private B, A-dbuf, 1 barrier/chunk ----
#define OFF_B0  0              // 16 KiB
#define OFF_B1  16384          // 16 KiB
#define OFF_A   32768          // 2 x 8 KiB (XOR-swizzled frag images)
#define OFF_POS 49152          // [2 qk][64 f][64 rows] bf16 = 16384 B
#define OFF_FR  65536          // 640 f32
#define OFF_CO  68096          // 640 f32
#define OFF_SO  70656          // 640 f32
#define SMEM_SZ 73216          // 71.5 KiB -> 2 blocks/CU

__global__ __launch_bounds__(512, 4)
void spe_main(const float* __restrict__ queries, const float* __restrict__ keys,
              const float* __restrict__ freqs, const float* __restrict__ offsets,
              const unsigned char* __restrict__ bpack, float* __restrict__ out)
{
    __shared__ __attribute__((aligned(16))) unsigned char smem[SMEM_SZ];
    const int tid  = threadIdx.x;
    const int lane = tid & 63;
    const int w    = tid >> 6;

    // XCD-locality decode (validated R13): bid&7 = h
    const int fb = blockIdx.x;              // 0..1023
    const int h  = fb & 7;
    const int b  = (fb >> 3) & 3;
    const int l0 = (fb >> 5) * 64;
    const int bh = b*NH + h;

    float* ld_fr = (float*)(smem + OFF_FR);
    float* ld_co = (float*)(smem + OFF_CO);
    float* ld_so = (float*)(smem + OFF_SO);
    unsigned short* pos_t = (unsigned short*)(smem + OFF_POS);

    for (int i = tid; i < NF*NK; i += 512) {
        const float fv = freqs[h*NF*NK + i];
        ld_fr[i] = 0.5f / (1.0f + expf(-fv));                                // rev/step
        const float xo = __builtin_amdgcn_fractf(offsets[h*NF*NK + i] * 0.15915494309189535f);
        ld_co[i] = __builtin_amdgcn_cosf(xo);
        ld_so[i] = __builtin_amdgcn_sinf(xo);
    }
    {   // pos tiles -> bf16 transposed [qk][f][64]
        const int r  = tid >> 2;            // 0..127: <64 q-row, >=64 k-row
        const int f0 = (tid & 3) * 16;
        const int rl = r & 63;
        const float* src = (r < 64)
            ? queries + ((size_t)((b*NL + l0 + rl)*NH + h))*NF + f0
            : keys    + ((size_t)((b*NL + l0 + rl)*NH + h))*NF + f0;
        unsigned short* pdst = pos_t + ((r >> 6) << 12);
        #pragma unroll
        for (int j = 0; j < 4; ++j) {
            const float4 v = *(const float4*)(src + j*4);
            const int f = f0 + j*4;
            pdst[(f+0)*64 + rl] = f2b(v.x);
            pdst[(f+1)*64 + rl] = f2b(v.y);
            pdst[(f+2)*64 + rl] = f2b(v.z);
            pdst[(f+3)*64 + rl] = f2b(v.w);
        }
    }
    __syncthreads();   // pos/cs tables visible

    const unsigned char* bp = bpack + (size_t)bh * ((size_t)NCH*NFRAG_B*1024);

    const int fn0 = w * 2;                  // this wave OWNS B col-frags 2w, 2w+1

    // issue B(t) -> Bbuf[t&1] (only the frags THIS wave reads; no duplication)
    auto issueB = [&](int t) {
        unsigned char* Bd = smem + ((t & 1) ? OFF_B1 : OFF_B0);
        const unsigned char* bsrc = bp + (size_t)t*NFRAG_B*1024;
        #pragma unroll
        for (int j = 0; j < 2; ++j)
            gload_lds16(bsrc + (size_t)(fn0 + j)*1024 + lane*16,
                        Bd + ((fn0 + j) << 10));
    };

    f32x4 acc[8][2];   // 8 row-frags (0-3 q, 4-7 k) x 2 col-frags = 64 AGPR
    #pragma unroll
    for (int mi = 0; mi < 8; ++mi)
        #pragma unroll
        for (int ni = 0; ni < 2; ++ni)
            acc[mi][ni] = (f32x4){0.f, 0.f, 0.f, 0.f};

    // A-synth map (R13-validated): rq = tid&63, oct = (tid>>6)&3, half = tid>>8
    const int rq   = tid & 63;
    const int oct  = (tid >> 6) & 3;
    const int half = tid >> 8;
    const float lf = (float)(l0 + rq);
    const unsigned short* posq = pos_t;
    const unsigned short* posk = pos_t + 4096;
    const int a_log_q = ((rq >> 4) << 10) + ((oct*16 + (rq & 15)) << 4) + (half << 3);
    const int aw_q = a_log_q ^ (((rq >> 4) & 3) << 5);
    const int aw_k = (a_log_q + 4096) ^ (((rq >> 4) & 3) << 5);

    auto synthA = [&](int t, u32x2& q01, u32x2& k01) {
        #pragma unroll
        for (int p = 0; p < 2; ++p) {
            const int kk   = t*BK + oct*8 + (half*2 + p)*2;   // even k
            const int f    = (kk*3277) >> 16;                 // kk/20
            const int srem = kk - f*20;
            const int kidx = f*NK + (srem >> 1);
            const float x  = __builtin_amdgcn_fractf(ld_fr[kidx] * lf);
            const float ck = __builtin_amdgcn_cosf(x);
            const float sk = __builtin_amdgcn_sinf(x);
            const float co = ld_co[kidx], so = ld_so[kidx];
            const float cq = ck*co - sk*so;                   // rotate by offset
            const float sq = sk*co + ck*so;
            const float pq = __uint_as_float(((unsigned)posq[f*64 + rq]) << 16);
            const float pk = __uint_as_float(((unsigned)posk[f*64 + rq]) << 16);
            q01[p] = cvtpk(cq*pq, sq*pq);
            k01[p] = cvtpk(ck*pk, sk*pk);
        }
    };

    // prologue: A(0) -> Abuf0, synth A(1) -> regs, issue B(0); barrier (A0 visible)
    u32x2 q01, k01;
    synthA(0, q01, k01);
    *(u32x2*)(smem + OFF_A + aw_q) = q01;       // Abuf0 (par=0)
    *(u32x2*)(smem + OFF_A + aw_k) = k01;
    issueB(0);
    synthA(1, q01, k01);
    __builtin_amdgcn_sched_barrier(0);
    __builtin_amdgcn_s_barrier();               // A(0) visible to all waves
    __builtin_amdgcn_sched_barrier(0);

    #pragma unroll 1
    for (int t = 0; t < NCH; ++t) {
        const int par = t & 1;

        if (t + 1 < NCH) {
            // write A(t+1) -> other A buffer (its MFMA(t-1) readers passed the barrier)
            const int np = (t + 1) & 1;
            *(u32x2*)(smem + OFF_A + np*8192 + aw_q) = q01;
            *(u32x2*)(smem + OFF_A + np*8192 + aw_k) = k01;
            issueB(t + 1);                       // Bbuf[(t+1)&1]; own reads(t-1) retired
        }
        if (t + 2 < NCH) synthA(t + 2, q01, k01);   // VALU (overlaps other waves' MFMA)

        // wave-local wait: B(t) landed (issued a full chunk ago; 2 newer loads allowed)
        if (t + 1 < NCH) { asm volatile("s_waitcnt vmcnt(2)" ::: "memory"); }
        else             { asm volatile("s_waitcnt vmcnt(0)" ::: "memory"); }
        __builtin_amdgcn_sched_barrier(0);

        const unsigned char* Bc = smem + (par ? OFF_B1 : OFF_B0);
        short8 bf[2];
        #pragma unroll
        for (int ni = 0; ni < 2; ++ni)
            bf[ni] = *(const short8*)(Bc + ((fn0 + ni) << 10) + (lane << 4));

        __builtin_amdgcn_s_setprio(1);          // T5: favor MFMA-phase wave vs other block
        #pragma unroll
        for (int mi = 0; mi < 8; ++mi) {         // all 8 A frags (q rows then k rows)
            const int aoff = (mi << 10) + (lane << 4);
            const short8 af = *(const short8*)(smem + OFF_A + par*8192
                                               + (aoff ^ ((mi & 3) << 5)));
            #pragma unroll
            for (int ni = 0; ni < 2; ++ni)
                acc[mi][ni] = __builtin_amdgcn_mfma_f32_16x16x32_bf16(af, bf[ni], acc[mi][ni], 0, 0, 0);
        }
        __builtin_amdgcn_s_setprio(0);

        if (t + 1 < NCH) {                       // end-of-chunk barrier (A protection)
            __builtin_amdgcn_sched_barrier(0);
            __builtin_amdgcn_s_barrier();
            __builtin_amdgcn_sched_barrier(0);
        }
    }

    // epilogue: mi>>2 selects q/k; rows (mi&3)*16; cols = wave strip w*32 + ni*16
    const size_t kofs = (size_t)NB*NL*NH*NR;
    const int row_l = (lane >> 4) * 4;
    const int col_r = lane & 15;
    #pragma unroll
    for (int mi = 0; mi < 8; ++mi) {
        const size_t qk_off = (mi >= 4) ? kofs : 0;
        const int lg = l0 + (mi & 3)*16 + row_l;
        #pragma unroll
        for (int ni = 0; ni < 2; ++ni) {
            const int rg = w*32 + ni*16 + col_r;
            const f32x4 v = acc[mi][ni];
            #pragma unroll
            for (int q = 0; q < 4; ++q)
                out[qk_off + ((size_t)((b*NL + lg + q)*NH + h))*NR + rg] = v[q];
        }
    }
}

// ---------------- fallback (validated R2 kernel) ----------------
#define FOFF_B   0
#define FOFF_A   32768
#define FOFF_POS 49152
#define FOFF_FR  65536
#define FOFF_OFS 68096
#define FOFF_GS  70656
#define FSMEM_SZ 73216

__global__ __launch_bounds__(512, 4)
void spe_mfma_fb(const float* __restrict__ queries, const float* __restrict__ keys,
                 const float* __restrict__ z, const float* __restrict__ freqs,
                 const float* __restrict__ offsets, const float* __restrict__ gains,
                 float* __restrict__ out)
{
    __shared__ __attribute__((aligned(16))) unsigned char smem[FSMEM_SZ];
    const int tid = threadIdx.x, lane = tid & 63;
    const int l0 = blockIdx.x * BM, bh = blockIdx.y;
    const int b = bh >> 3, h = bh & 7, isK = blockIdx.z;
    float* ld_fr = (float*)(smem + FOFF_FR);
    float* ld_of = (float*)(smem + FOFF_OFS);
    float* ld_gs = (float*)(smem + FOFF_GS);
    unsigned short* pos_t = (unsigned short*)(smem + FOFF_POS);
    for (int i = tid; i < NF*NK; i += 512) {
        const float fv = freqs[h*NF*NK + i];
        ld_fr[i] = 0.5f / (1.0f + expf(-fv));
        ld_of[i] = isK ? 0.0f : offsets[h*NF*NK + i] * 0.15915494309189535f;
        ld_gs[i] = log1pf(expf(gains[h*NF*NK + i])) * 0.0078125f;
    }
    {
        const float* pos = isK ? keys : queries;
        #pragma unroll
        for (int i = 0; i < 4; ++i) {
            const int lrow = (tid >> 4) + 32*i;
            const int f0 = (tid & 15) * 4;
            const float4 v = *(const float4*)(pos + ((size_t)((b*NL + l0 + lrow)*NH + h))*NF + f0);
            pos_t[(f0+0)*BM + lrow] = f2b(v.x); pos_t[(f0+1)*BM + lrow] = f2b(v.y);
            pos_t[(f0+2)*BM + lrow] = f2b(v.z); pos_t[(f0+3)*BM + lrow] = f2b(v.w);
        }
    }
    __syncthreads();
    const int w = tid >> 6, wm = w >> 2, wn = w & 3;
    f32x4 acc[4][4];
    #pragma unroll
    for (int mi = 0; mi < 4; ++mi)
        #pragma unroll
        for (int ni = 0; ni < 4; ++ni) acc[mi][ni] = (f32x4){0.f,0.f,0.f,0.f};
    const float* zbh = z + (size_t)(b*NH + h) * ((size_t)KTOT*NR);
    for (int ch = 0; ch < KTOT/64; ++ch) {
        const int fs0 = ch * 64;
        #pragma unroll
        for (int i = 0; i < 4; ++i) {
            const int tau = tid + 512*i, r = tau & 255, krun = tau >> 8;
            const float* zp = zbh + (size_t)(fs0 + krun*8)*NR + r;
            u32x4 wv2;
            #pragma unroll
            for (int jp = 0; jp < 4; ++jp) {
                const int fs = fs0 + krun*8 + 2*jp;
                const int f = (fs*3277) >> 16; const int rem = fs - f*20;
                const int km = (rem >= NK) ? rem - NK : rem;
                const int kn = ((rem+1) >= NK && (rem+1) < 2*NK) ? rem+1-NK : rem+1;
                const float sc0 = ld_gs[f*NK + km], sc1 = ld_gs[f*NK + (kn < NK ? kn : kn-NK)];
                wv2[jp] = pk2(zp[(2*jp)*NR]*sc0, zp[(2*jp+1)*NR]*sc1);
            }
            *(u32x4*)(smem + FOFF_B + ((((krun>>2)*16) + (r>>4)) << 10)
                                    + ((((krun&3)*16) + (r&15)) << 4)) = wv2;
        }
        #pragma unroll
        for (int i = 0; i < 2; ++i) {
            const int tau = tid + 512*i, m = tau & 127, krun = tau >> 7;
            const float lff = (float)(l0 + m);
            u32x4 wv2;
            #pragma unroll
            for (int jp = 0; jp < 4; ++jp) {
                const int fs = fs0 + krun*8 + 2*jp;
                const int f = (fs*3277) >> 16; const int rem = fs - f*20;
                const int kidx = f*NK + (rem >> 1);
                const float x = __builtin_amdgcn_fractf(ld_of[kidx] + ld_fr[kidx]*lff);
                const float c = __builtin_amdgcn_cosf(x), sn = __builtin_amdgcn_sinf(x);
                const float p = __uint_as_float(((unsigned)pos_t[f*BM + m]) << 16);
                wv2[jp] = pk2(c*p, sn*p);
            }
            *(u32x4*)(smem + FOFF_A + ((((krun>>2)*8) + (m>>4)) << 10)
                                    + ((((krun&3)*16) + (m&15)) << 4)) = wv2;
        }
        __syncthreads();
        #pragma unroll
        for (int ks = 0; ks < 2; ++ks) {
            short8 bf[4];
            #pragma unroll
            for (int ni = 0; ni < 4; ++ni)
                bf[ni] = *(const short8*)(smem + FOFF_B + ((ks*16 + wn*4 + ni) << 10) + (lane << 4));
            #pragma unroll
            for (int mi = 0; mi < 4; ++mi) {
                const short8 af = *(const short8*)(smem + FOFF_A + ((ks*8 + wm*4 + mi) << 10) + (lane << 4));
                #pragma unroll
                for (int ni = 0; ni < 4; ++ni)
                    acc[mi][ni] = __builtin_amdgcn_mfma_f32_16x16x32_bf16(af, bf[ni], acc[mi][ni], 0, 0, 0);
            }
        }
        __syncthreads();
    }
    const size_t qk_off = (size_t)isK * ((size_t)NB*NL*NH*NR);
    const int row_l = (lane >> 4) * 4, col_r = lane & 15;
    #pragma unroll
    for (int mi = 0; mi < 4; ++mi) {
        const int lg = l0 + wm*64 + mi*16 + row_l;
        #pragma unroll
        for (int ni = 0; ni < 4; ++ni) {
            const int rg = wn*64 + ni*16 + col_r;
            const f32x4 v = acc[mi][ni];
            #pragma unroll
            for (int q = 0; q < 4; ++q)
                out[qk_off + ((size_t)((b*NL + lg + q)*NH + h))*NR + rg] = v[q];
        }
    }
}

extern "C" void kernel_launch(void* const* d_in, const int* in_sizes, int n_in,
                              void* d_out, int out_size, void* d_ws, size_t ws_size,
                              hipStream_t stream) {
    const float* queries = (const float*)d_in[0];
    const float* keys    = (const float*)d_in[1];
    const float* z       = (const float*)d_in[2];
    const float* freqs   = (const float*)d_in[3];
    const float* offsets = (const float*)d_in[4];
    const float* gains   = (const float*)d_in[5];
    float* out = (float*)d_out;

    if (ws_size >= WS_NEEDED) {
        unsigned char* bpack = (unsigned char*)d_ws;
        spe_prep<<<dim3(NCH, NB*NH), 256, 0, stream>>>(z, gains, bpack);
        spe_main<<<dim3(1024), 512, 0, stream>>>(queries, keys, freqs, offsets, bpack, out);
    } else {
        spe_mfma_fb<<<dim3(NL/BM, NB*NH, 2), 512, 0, stream>>>(queries, keys, z, freqs, offsets, gains, out);
    }
}